// Round 1
// baseline (97.853 us; speedup 1.0000x reference)
//
#include <hip/hip_runtime.h>

// Inverse Haar wavelet transform: [B,H,W,4C] f32 -> [B,2H,2W,C] f32
// B=16, H=W=128, C4=256, n=64.
//
// out[b,2h  ,2w  ,c] = 0.5*(a1 - a2 - a3 + a4)
// out[b,2h  ,2w+1,c] = 0.5*(a1 + a2 - a3 - a4)
// out[b,2h+1,2w  ,c] = 0.5*(a1 - a2 + a3 - a4)
// out[b,2h+1,2w+1,c] = 0.5*(a1 + a2 + a3 + a4)
// where a_g = in[b,h,w,(g-1)*64 + c].
//
// One thread per (pixel, float4-of-channels): 16 threads cover the 64 output
// channels of one input pixel. All loads/stores are 16B per lane, contiguous
// in 256B chunks -> fully coalesced, no partial cachelines.

#define H 128
#define W 128
#define NPIX (16 * H * W)          // 262144 pixels
#define THREADS_TOTAL (NPIX * 16)  // 4194304

__global__ __launch_bounds__(256) void iwt_kernel(
    const float4* __restrict__ in, float4* __restrict__ out) {
    int tid = blockIdx.x * blockDim.x + threadIdx.x;

    int c4  = tid & 15;   // which float4 within the 64 channels
    int pix = tid >> 4;   // b*H*W + h*W + w

    int w = pix & (W - 1);
    int h = (pix >> 7) & (H - 1);
    int b = pix >> 14;

    // Input pixel: 256 floats = 64 float4. Group g at float4-offset g*16 + c4.
    const float4* p = in + (size_t)pix * 64;
    float4 a1 = p[c4];
    float4 a2 = p[16 + c4];
    float4 a3 = p[32 + c4];
    float4 a4 = p[48 + c4];

    float4 ee, eo, oe, oo;
    ee.x = 0.5f * (a1.x - a2.x - a3.x + a4.x);
    ee.y = 0.5f * (a1.y - a2.y - a3.y + a4.y);
    ee.z = 0.5f * (a1.z - a2.z - a3.z + a4.z);
    ee.w = 0.5f * (a1.w - a2.w - a3.w + a4.w);

    eo.x = 0.5f * (a1.x + a2.x - a3.x - a4.x);
    eo.y = 0.5f * (a1.y + a2.y - a3.y - a4.y);
    eo.z = 0.5f * (a1.z + a2.z - a3.z - a4.z);
    eo.w = 0.5f * (a1.w + a2.w - a3.w - a4.w);

    oe.x = 0.5f * (a1.x - a2.x + a3.x - a4.x);
    oe.y = 0.5f * (a1.y - a2.y + a3.y - a4.y);
    oe.z = 0.5f * (a1.z - a2.z + a3.z - a4.z);
    oe.w = 0.5f * (a1.w - a2.w + a3.w - a4.w);

    oo.x = 0.5f * (a1.x + a2.x + a3.x + a4.x);
    oo.y = 0.5f * (a1.y + a2.y + a3.y + a4.y);
    oo.z = 0.5f * (a1.z + a2.z + a3.z + a4.z);
    oo.w = 0.5f * (a1.w + a2.w + a3.w + a4.w);

    // Output: [B, 2H, 2W, 64] f32 = [B, 2H, 2W, 16] float4.
    // Output pixel index of (2h, 2w):
    size_t opix = ((size_t)b * (2 * H) + 2 * h) * (2 * W) + 2 * w;
    out[(opix)            * 16 + c4] = ee;  // (2h,   2w)
    out[(opix + 1)        * 16 + c4] = eo;  // (2h,   2w+1)
    out[(opix + 2 * W)    * 16 + c4] = oe;  // (2h+1, 2w)
    out[(opix + 2 * W + 1)* 16 + c4] = oo;  // (2h+1, 2w+1)
}

extern "C" void kernel_launch(void* const* d_in, const int* in_sizes, int n_in,
                              void* d_out, int out_size, void* d_ws, size_t ws_size,
                              hipStream_t stream) {
    const float4* in = (const float4*)d_in[0];
    float4* out = (float4*)d_out;
    const int block = 256;
    const int grid = THREADS_TOTAL / block;  // 16384
    iwt_kernel<<<grid, block, 0, stream>>>(in, out);
}

// Round 2
// 80.510 us; speedup vs baseline: 1.2154x; 1.2154x over previous
//
#include <hip/hip_runtime.h>

// Inverse Haar wavelet transform: [B,H,W,4C] f32 -> [B,2H,2W,C] f32
// B=16, H=W=128, C4=256, n=64.
//
// out[b,2h  ,2w  ,c] = 0.5*(a1 - a2 - a3 + a4)
// out[b,2h  ,2w+1,c] = 0.5*(a1 + a2 - a3 - a4)
// out[b,2h+1,2w  ,c] = 0.5*(a1 - a2 + a3 - a4)
// out[b,2h+1,2w+1,c] = 0.5*(a1 + a2 + a3 + a4)
//
// One thread per (pixel, float4-of-channels). All loads/stores 16B/lane,
// full-cacheline coalesced. Output stores are NONTEMPORAL: output has zero
// reuse, and streaming it past the caches lets the 256 MiB input stay
// resident in the 256 MiB Infinity Cache across replays -> reads become
// L3 hits instead of HBM fetches.

#define H 128
#define W 128
#define NPIX (16 * H * W)          // 262144 pixels
#define THREADS_TOTAL (NPIX * 16)  // 4194304

typedef float f4 __attribute__((ext_vector_type(4)));

__global__ __launch_bounds__(256) void iwt_kernel(
    const f4* __restrict__ in, f4* __restrict__ out) {
    int tid = blockIdx.x * blockDim.x + threadIdx.x;

    int c4  = tid & 15;   // which float4 within the 64 channels
    int pix = tid >> 4;   // b*H*W + h*W + w

    int w = pix & (W - 1);
    int h = (pix >> 7) & (H - 1);
    int b = pix >> 14;

    // Input pixel: 256 floats = 64 float4. Group g at float4-offset g*16 + c4.
    const f4* p = in + (size_t)pix * 64;
    f4 a1 = p[c4];
    f4 a2 = p[16 + c4];
    f4 a3 = p[32 + c4];
    f4 a4 = p[48 + c4];

    f4 ee = 0.5f * (a1 - a2 - a3 + a4);  // (2h,   2w)
    f4 eo = 0.5f * (a1 + a2 - a3 - a4);  // (2h,   2w+1)
    f4 oe = 0.5f * (a1 - a2 + a3 - a4);  // (2h+1, 2w)
    f4 oo = 0.5f * (a1 + a2 + a3 + a4);  // (2h+1, 2w+1)

    // Output: [B, 2H, 2W, 64] f32 = [B, 2H, 2W, 16] f4.
    size_t opix = ((size_t)b * (2 * H) + 2 * h) * (2 * W) + 2 * w;
    __builtin_nontemporal_store(ee, &out[(opix)             * 16 + c4]);
    __builtin_nontemporal_store(eo, &out[(opix + 1)         * 16 + c4]);
    __builtin_nontemporal_store(oe, &out[(opix + 2 * W)     * 16 + c4]);
    __builtin_nontemporal_store(oo, &out[(opix + 2 * W + 1) * 16 + c4]);
}

extern "C" void kernel_launch(void* const* d_in, const int* in_sizes, int n_in,
                              void* d_out, int out_size, void* d_ws, size_t ws_size,
                              hipStream_t stream) {
    const f4* in = (const f4*)d_in[0];
    f4* out = (f4*)d_out;
    const int block = 256;
    const int grid = THREADS_TOTAL / block;  // 16384
    iwt_kernel<<<grid, block, 0, stream>>>(in, out);
}